// Round 7
// baseline (12862.906 us; speedup 1.0000x reference)
//
#include <hip/hip_runtime.h>
#include <hip/hip_fp16.h>
#include <math.h>

// ---------------- constants ----------------
#define T_STEPS 8192
#define IN_DIM  1024
#define HD      1024
#define ZD      4096          // 4 gates * HD, order [i, j, f, o]
#define G2      64            // phase-2 workgroups (each owns 16 h-cols x 4 gates)
#define B2      512           // phase-2 block size (8 waves)

typedef short  short8 __attribute__((ext_vector_type(8)));
typedef float  f32x4  __attribute__((ext_vector_type(4)));
typedef unsigned uint4v __attribute__((ext_vector_type(4)));
typedef _Float16 h2v __attribute__((ext_vector_type(2)));

__device__ __forceinline__ unsigned short f2bf(float f) {
    unsigned u = __float_as_uint(f);
    unsigned r = (u + 0x7fffu + ((u >> 16) & 1u)) >> 16;
    return (unsigned short)r;
}

// pack 2 fp32 -> 2 fp16 (RTZ) as a dword; bit_cast bridges __fp16 vs _Float16 types
__device__ __forceinline__ unsigned pk16(float a, float b) {
    return __builtin_bit_cast(unsigned, __builtin_amdgcn_cvt_pkrtz(a, b));
}

// ---------------- phase 0: pack Wx (rows 0..1023 of W) into bf16 tile layout ----
__global__ void wt_pack(const float* __restrict__ W, unsigned short* __restrict__ Wt) {
    int idx = blockIdx.x * 256 + threadIdx.x;      // 0 .. 4M-1
    int k = idx >> 12;                             // 0..1023
    int c = idx & 4095;                            // 0..4095
    float v = W[(size_t)k * ZD + c];               // coalesced read
    int tn = c >> 7, col = c & 127;
    int tk = k >> 5, kk = k & 31;
    Wt[(((size_t)(tn * 32 + tk) * 128 + col) << 5) + kk] = f2bf(v);
}

// ---------------- phase 0b: pack Wh (rows 1024..2047) into fp16 per-thread runs --
__global__ void whp_pack(const float* __restrict__ W, unsigned* __restrict__ Whp) {
    int i = blockIdx.x * 256 + threadIdx.x;   // 0..32767
    int zcol = i & 4095;
    int seg  = i >> 12;                       // 0..7
    const float* src = W + (size_t)(IN_DIM + (seg << 7)) * ZD + zcol; // lane-coalesced
    unsigned* dst = Whp + ((size_t)zcol * 8 + seg) * 64;              // 256B/thread
    for (int j = 0; j < 64; ++j) {
        float v0 = src[(size_t)(2 * j) * ZD];
        float v1 = src[(size_t)(2 * j + 1) * ZD];
        unsigned lo = (unsigned)__half_as_ushort(__float2half(v0));
        unsigned hi = (unsigned)__half_as_ushort(__float2half(v1));
        dst[j] = lo | (hi << 16);
    }
}

// ---------------- phase 1: ZX = x @ Wx + b (bf16 MFMA, fp32 accum) --------------
#define BM 128
#define BN 128
#define BKK 32
#define LDA 40    // padded LDS stride (bf16 elems)

__global__ __launch_bounds__(256) void zx_gemm(const float* __restrict__ x,
                                               const unsigned short* __restrict__ Wt,
                                               const float* __restrict__ b,
                                               float* __restrict__ zx) {
    __shared__ unsigned short As[128 * LDA];
    __shared__ unsigned short Bs[128 * LDA];
    const int tid  = threadIdx.x;
    const int wave = tid >> 6, lane = tid & 63;
    const int wr = wave & 1, wc = wave >> 1;
    const int m0 = blockIdx.y * BM, n0 = blockIdx.x * BN;
    const int quad = lane >> 4, l16 = lane & 15;

    f32x4 acc[4][4] = {};
    float bias[4];
#pragma unroll
    for (int j = 0; j < 4; ++j) bias[j] = b[n0 + wc * 64 + j * 16 + l16];

    for (int it = 0; it < IN_DIM / BKK; ++it) {
        const int k0 = it * BKK;
        // stage A: x[m0..+127][k0..+31] fp32 -> bf16 LDS
        {
            int r  = tid >> 3;          // 0..31
            int k4 = (tid & 7) * 4;
#pragma unroll
            for (int p = 0; p < 4; ++p) {
                int rr = r + p * 32;
                float4 v = *(const float4*)&x[(size_t)(m0 + rr) * IN_DIM + k0 + k4];
                unsigned p0 = (unsigned)f2bf(v.x) | ((unsigned)f2bf(v.y) << 16);
                unsigned p1 = (unsigned)f2bf(v.z) | ((unsigned)f2bf(v.w) << 16);
                *(uint2*)&As[rr * LDA + k4] = make_uint2(p0, p1);
            }
        }
        // stage B: pre-packed contiguous 8KB tile -> LDS (pad stride 40)
        {
            const uint4* src = (const uint4*)(Wt + ((size_t)(n0 >> 7) * 32 + it) * 4096);
#pragma unroll
            for (int p = 0; p < 2; ++p) {
                int id = tid * 2 + p;           // 0..511
                int col = id >> 2, kp = id & 3;
                uint4 v = src[id];
                *(uint4*)&Bs[col * LDA + kp * 8] = v;
            }
        }
        __syncthreads();
        short8 af[4], bfr[4];
#pragma unroll
        for (int i = 0; i < 4; ++i)
            af[i] = *(const short8*)&As[(wr * 64 + i * 16 + l16) * LDA + quad * 8];
#pragma unroll
        for (int j = 0; j < 4; ++j)
            bfr[j] = *(const short8*)&Bs[(wc * 64 + j * 16 + l16) * LDA + quad * 8];
#pragma unroll
        for (int i = 0; i < 4; ++i)
#pragma unroll
            for (int j = 0; j < 4; ++j)
                acc[i][j] = __builtin_amdgcn_mfma_f32_16x16x32_bf16(af[i], bfr[j], acc[i][j], 0, 0, 0);
        __syncthreads();
    }
    // epilogue: D row = quad*4 + reg, col = l16
#pragma unroll
    for (int i = 0; i < 4; ++i) {
        int row = m0 + wr * 64 + i * 16 + quad * 4;
#pragma unroll
        for (int j = 0; j < 4; ++j) {
            int col = n0 + wc * 64 + j * 16 + l16;
#pragma unroll
            for (int r = 0; r < 4; ++r)
                zx[(size_t)(row + r) * ZD + col] = acc[i][j][r] + bias[j];
        }
    }
}

// ---------------- fast activations (critical path) ----------------
__device__ __forceinline__ float sigmoid_fast(float x) {
    float e = __expf(-x);
    return __builtin_amdgcn_rcpf(1.f + e);
}
__device__ __forceinline__ float tanh_fast(float x) {
    float e = __expf(2.f * x);
    return 1.f - 2.f * __builtin_amdgcn_rcpf(e + 1.f);
}

// ---------------- phase 2: sequential recurrence (cooperative, 64 WGs) ----------
// Base = round-5 PASSING kernel (12.2ms). One fix, found by vmcnt-semantics audit:
// ROUND-5 BUG: wave1 issued its zx prefetch (cold ~500-900cy load) right BEFORE
// the spin; the spin's `s_waitcnt vmcnt(0)` is WAVE-level and IN-ORDER, so wave1's
// first tag check of every step waited out the full zx latency, and sync2 made the
// whole WG wait for wave1. The "prefetch" was ON the critical path every step.
// FIX: wave1 issues the row s+2 load AFTER its detect (so it has dot2+sync2+next
// spin-wait ~600-1000cy to retire before the next vmcnt(0)), parks row s+1 after
// dot2. zx_lds becomes a quad buffer: write slot (s+1)&3 at step s, read slot s&3.
// Hazard audit (one sync2/step, as before):
//  * zx_lds slot k written at step s (k=(s+1)&3, pre-sync2(s)); readers of slot k:
//    wave0 C(s+1) after sync2(s+1) [ordered], and old C(s-3) which precedes
//    sync2(s-2) <= sync2(s-1) < write [ordered]. Safe.
//  * lds_hh / pbuf audits unchanged from round 5.
// Prologue: row1 load issued FIRST thing in the kernel so spin(0) is clean.
__global__ __launch_bounds__(B2, 2) void lstm_seq(const unsigned* __restrict__ whp,
                                                  const float* __restrict__ zx,
                                                  float* __restrict__ out,
                                                  unsigned* hslot) {
    __shared__ unsigned lds_hh[512];       // fp16-packed h: dword d = {h[2d], h[2d+1]}
    __shared__ float pbuf[2][B2];
    __shared__ float zx_lds[4][64];        // quad-buffered zx rows
    const int g    = blockIdx.x;
    const int t    = threadIdx.x;
    const int seg  = t >> 6;           // 0..7 == wave index
    const int lane = t & 63;
    const int gate = lane >> 4;        // 0..3  [i,j,f,o]
    const int cidx = lane & 15;
    const int zcol = g * 16 + cidx + (gate << 10);
    const int zoff = (gate << 10) + g * 16 + cidx;   // wave-1 zx lane mapping (l=lane)

    const bool w1 = (t >= 64 && t < 128);

    // EARLY: wave1 issues zx row 1 load first (retires during prologue, so the
    // step-0 spin's vmcnt(0) is clean)
    float znext = 0.f;
    if (w1) znext = zx[(size_t)1 * ZD + zoff];

    // ---- Wh slice -> 64 packed-fp16 dwords (streamed/hoisted by compiler;
    // rounds 1/3 showed pinning is harmful-or-neutral — latency hides in the spin)
    unsigned wp[64];
    {
        const unsigned* wsrc = whp + ((size_t)zcol * 8 + seg) * 64;
#pragma unroll
        for (int j = 0; j < 64; ++j) wp[j] = wsrc[j];
    }

    // zx row 0 -> slot 0 (direct)
    if (w1) zx_lds[0][lane] = zx[(size_t)0 * ZD + zoff];
    __syncthreads();   // cover zx_lds[0] for step-0 C-phase (outside the loop)

    float c_state = 0.f;

    for (int s = 0; s < T_STEPS; ++s) {
        const int par = s & 1;
        // ---- A: acquire own slice — lanes 0..31 poll 16B = 4 tagged packets.
        // No pre-spin vmem issue anywhere: every wave's vmcnt(0) sees only the
        // poll load (wave1's row-s+2 load from step s-1 is ~1 step old). ----
        if (lane < 32) {
            const unsigned want = (unsigned)(s & 255);
            const unsigned* ap = hslot + (par << 10) + (seg << 7) + (lane << 2);
            uint4v pv;
            for (;;) {
                asm volatile("global_load_dwordx4 %0, %1, off sc0 sc1\n\t"
                             "s_waitcnt vmcnt(0)"
                             : "=v"(pv) : "v"(ap) : "memory");
                unsigned bad = ((pv.x ^ want) | (pv.y ^ want) |
                                (pv.z ^ want) | (pv.w ^ want)) & 255u;
                if (bad == 0) break;
            }
            // convert 4 fp32 packets -> 2 packed-fp16 dwords (tag bits sub-ulp)
            unsigned d0 = pk16(__uint_as_float(pv.x), __uint_as_float(pv.y));
            unsigned d1 = pk16(__uint_as_float(pv.z), __uint_as_float(pv.w));
            *(uint2*)&lds_hh[(seg << 6) + 2 * lane] = make_uint2(d0, d1);
        }
        // wave1: issue zx row s+2 NOW (post-detect) — ~600-1000cy to retire before
        // its next spin's vmcnt(0); znext (row s+1) arrived during step s-1.
        float zissue = 0.f;
        if (w1 && s + 2 < T_STEPS) zissue = zx[(size_t)(s + 2) * ZD + zoff];
        // ---- B: 64 dot2 against fp16 weights (own slice) ----
        float a0 = 0.f, a1 = 0.f, a2 = 0.f, a3 = 0.f;
        const uint4* hp = (const uint4*)&lds_hh[seg << 6];
#pragma unroll
        for (int j = 0; j < 16; ++j) {
            uint4 hv = hp[j];    // same addr across wave: LDS broadcast, no conflict
            a0 = __builtin_amdgcn_fdot2(__builtin_bit_cast(h2v, wp[4 * j + 0]),
                                        __builtin_bit_cast(h2v, hv.x), a0, false);
            a1 = __builtin_amdgcn_fdot2(__builtin_bit_cast(h2v, wp[4 * j + 1]),
                                        __builtin_bit_cast(h2v, hv.y), a1, false);
            a2 = __builtin_amdgcn_fdot2(__builtin_bit_cast(h2v, wp[4 * j + 2]),
                                        __builtin_bit_cast(h2v, hv.z), a2, false);
            a3 = __builtin_amdgcn_fdot2(__builtin_bit_cast(h2v, wp[4 * j + 3]),
                                        __builtin_bit_cast(h2v, hv.w), a3, false);
        }
        pbuf[par][t] = (a0 + a1) + (a2 + a3);
        // park row s+1 (loaded last step) into slot (s+1)&3; rotate the pipeline
        if (w1) {
            if (s + 1 < T_STEPS) zx_lds[(s + 1) & 3][lane] = znext;
            znext = zissue;
        }
        __syncthreads();                         // the ONLY barrier per step
        // ---- C: wave 0 reduces, gates, publishes ----
        if (t < 64) {
            float z = zx_lds[s & 3][t];
#pragma unroll
            for (int ss = 0; ss < 8; ++ss) z += pbuf[par][(ss << 6) + t];
            float zi = __shfl(z, cidx);
            float zj = __shfl(z, 16 + cidx);
            float zf = __shfl(z, 32 + cidx);
            float zo = __shfl(z, 48 + cidx);
            if (t < 16) {
                float fg = sigmoid_fast(zf + 1.0f);   // FORGET_BIAS = 1.0
                float ig = sigmoid_fast(zi);
                float og = sigmoid_fast(zo);
                c_state = c_state * fg + ig * tanh_fast(zj);
                float h = tanh_fast(c_state) * og;
                // pack: round h to 24-bit mantissa, tag in low 8 bits; 16 lanes
                // publish one contiguous 64B line per WG
                unsigned hb  = (__float_as_uint(h) + 0x80u) & 0xFFFFFF00u;
                unsigned pkt = hb | (unsigned)((s + 1) & 255);
                __hip_atomic_store(hslot + (((s + 1) & 1) << 10) + g * 16 + t, pkt,
                                   __ATOMIC_RELAXED, __HIP_MEMORY_SCOPE_AGENT);
                out[(size_t)s * HD + g * 16 + t] = h;  // off critical path
            }
        }
    }
}

// ---------------- launch ----------------
extern "C" void kernel_launch(void* const* d_in, const int* in_sizes, int n_in,
                              void* d_out, int out_size, void* d_ws, size_t ws_size,
                              hipStream_t stream) {
    const float* x = (const float*)d_in[0];   // [8192,1024]
    const float* W = (const float*)d_in[1];   // [2048,4096]
    const float* b = (const float*)d_in[2];   // [4096]
    float* out = (float*)d_out;               // [8192,1024]

    char* ws = (char*)d_ws;
    // ws layout: zx 128MB | hslot 16KB region (8KB used) | Wt/Whp 8MB (time-shared)
    float*          zxp   = (float*)ws;
    const size_t    ZXB   = (size_t)T_STEPS * ZD * sizeof(float);   // 134217728
    unsigned*       hslot = (unsigned*)(ws + ZXB);
    unsigned short* Wt    = (unsigned short*)(ws + ZXB + 16384);
    unsigned*       Whp   = (unsigned*)(ws + ZXB + 16384);          // reuses Wt region

    // h_0 = 0 with tag 0 in both parity slots (ws is poisoned each call)
    hipMemsetAsync(hslot, 0, 8192, stream);

    // phase 0: pack Wx -> bf16 tiles
    wt_pack<<<dim3((IN_DIM * ZD) / 256), dim3(256), 0, stream>>>(W, Wt);

    // phase 1: ZX = x @ Wx + b
    zx_gemm<<<dim3(ZD / BN, T_STEPS / BM), dim3(256), 0, stream>>>(x, Wt, b, zxp);

    // phase 0b: pack Wh -> fp16 pairs into the now-dead Wt region (stream-ordered)
    whp_pack<<<dim3(128), dim3(256), 0, stream>>>(W, Whp);

    // phase 2: sequential recurrence (cooperative for guaranteed co-residency)
    void* args[] = { (void*)&Whp, (void*)&zxp, (void*)&out, (void*)&hslot };
    hipLaunchCooperativeKernel((void*)lstm_seq, dim3(G2), dim3(B2), args, 0, stream);
}

// Round 8
// 12421.803 us; speedup vs baseline: 1.0355x; 1.0355x over previous
//
#include <hip/hip_runtime.h>
#include <hip/hip_fp16.h>
#include <math.h>

// ---------------- constants ----------------
#define T_STEPS 8192
#define IN_DIM  1024
#define HD      1024
#define ZD      4096          // 4 gates * HD, order [i, j, f, o]
#define G2      64            // phase-2 active workgroups (16 h-cols x 4 gates each)
#define NWG     512           // big-grid launch: 2/CU device-wide; 64 land on 1 XCD
#define B2      512           // phase-2 block size (8 waves)

typedef short  short8 __attribute__((ext_vector_type(8)));
typedef float  f32x4  __attribute__((ext_vector_type(4)));
typedef unsigned uint4v __attribute__((ext_vector_type(4)));
typedef _Float16 h2v __attribute__((ext_vector_type(2)));

__device__ __forceinline__ unsigned short f2bf(float f) {
    unsigned u = __float_as_uint(f);
    unsigned r = (u + 0x7fffu + ((u >> 16) & 1u)) >> 16;
    return (unsigned short)r;
}

// pack 2 fp32 -> 2 fp16 (RTZ) as a dword; bit_cast bridges __fp16 vs _Float16 types
__device__ __forceinline__ unsigned pk16(float a, float b) {
    return __builtin_bit_cast(unsigned, __builtin_amdgcn_cvt_pkrtz(a, b));
}

// ---------------- phase 0: pack Wx (rows 0..1023 of W) into bf16 tile layout ----
__global__ void wt_pack(const float* __restrict__ W, unsigned short* __restrict__ Wt) {
    int idx = blockIdx.x * 256 + threadIdx.x;      // 0 .. 4M-1
    int k = idx >> 12;                             // 0..1023
    int c = idx & 4095;                            // 0..4095
    float v = W[(size_t)k * ZD + c];               // coalesced read
    int tn = c >> 7, col = c & 127;
    int tk = k >> 5, kk = k & 31;
    Wt[(((size_t)(tn * 32 + tk) * 128 + col) << 5) + kk] = f2bf(v);
}

// ---------------- phase 0b: pack Wh (rows 1024..2047) into fp16 per-thread runs --
__global__ void whp_pack(const float* __restrict__ W, unsigned* __restrict__ Whp) {
    int i = blockIdx.x * 256 + threadIdx.x;   // 0..32767
    int zcol = i & 4095;
    int seg  = i >> 12;                       // 0..7
    const float* src = W + (size_t)(IN_DIM + (seg << 7)) * ZD + zcol; // lane-coalesced
    unsigned* dst = Whp + ((size_t)zcol * 8 + seg) * 64;              // 256B/thread
    for (int j = 0; j < 64; ++j) {
        float v0 = src[(size_t)(2 * j) * ZD];
        float v1 = src[(size_t)(2 * j + 1) * ZD];
        unsigned lo = (unsigned)__half_as_ushort(__float2half(v0));
        unsigned hi = (unsigned)__half_as_ushort(__float2half(v1));
        dst[j] = lo | (hi << 16);
    }
}

// ---------------- phase 1: ZX = x @ Wx + b (bf16 MFMA, fp32 accum) --------------
#define BM 128
#define BN 128
#define BKK 32
#define LDA 40    // padded LDS stride (bf16 elems)

__global__ __launch_bounds__(256) void zx_gemm(const float* __restrict__ x,
                                               const unsigned short* __restrict__ Wt,
                                               const float* __restrict__ b,
                                               float* __restrict__ zx) {
    __shared__ unsigned short As[128 * LDA];
    __shared__ unsigned short Bs[128 * LDA];
    const int tid  = threadIdx.x;
    const int wave = tid >> 6, lane = tid & 63;
    const int wr = wave & 1, wc = wave >> 1;
    const int m0 = blockIdx.y * BM, n0 = blockIdx.x * BN;
    const int quad = lane >> 4, l16 = lane & 15;

    f32x4 acc[4][4] = {};
    float bias[4];
#pragma unroll
    for (int j = 0; j < 4; ++j) bias[j] = b[n0 + wc * 64 + j * 16 + l16];

    for (int it = 0; it < IN_DIM / BKK; ++it) {
        const int k0 = it * BKK;
        // stage A: x[m0..+127][k0..+31] fp32 -> bf16 LDS
        {
            int r  = tid >> 3;          // 0..31
            int k4 = (tid & 7) * 4;
#pragma unroll
            for (int p = 0; p < 4; ++p) {
                int rr = r + p * 32;
                float4 v = *(const float4*)&x[(size_t)(m0 + rr) * IN_DIM + k0 + k4];
                unsigned p0 = (unsigned)f2bf(v.x) | ((unsigned)f2bf(v.y) << 16);
                unsigned p1 = (unsigned)f2bf(v.z) | ((unsigned)f2bf(v.w) << 16);
                *(uint2*)&As[rr * LDA + k4] = make_uint2(p0, p1);
            }
        }
        // stage B: pre-packed contiguous 8KB tile -> LDS (pad stride 40)
        {
            const uint4* src = (const uint4*)(Wt + ((size_t)(n0 >> 7) * 32 + it) * 4096);
#pragma unroll
            for (int p = 0; p < 2; ++p) {
                int id = tid * 2 + p;           // 0..511
                int col = id >> 2, kp = id & 3;
                uint4 v = src[id];
                *(uint4*)&Bs[col * LDA + kp * 8] = v;
            }
        }
        __syncthreads();
        short8 af[4], bfr[4];
#pragma unroll
        for (int i = 0; i < 4; ++i)
            af[i] = *(const short8*)&As[(wr * 64 + i * 16 + l16) * LDA + quad * 8];
#pragma unroll
        for (int j = 0; j < 4; ++j)
            bfr[j] = *(const short8*)&Bs[(wc * 64 + j * 16 + l16) * LDA + quad * 8];
#pragma unroll
        for (int i = 0; i < 4; ++i)
#pragma unroll
            for (int j = 0; j < 4; ++j)
                acc[i][j] = __builtin_amdgcn_mfma_f32_16x16x32_bf16(af[i], bfr[j], acc[i][j], 0, 0, 0);
        __syncthreads();
    }
    // epilogue: D row = quad*4 + reg, col = l16
#pragma unroll
    for (int i = 0; i < 4; ++i) {
        int row = m0 + wr * 64 + i * 16 + quad * 4;
#pragma unroll
        for (int j = 0; j < 4; ++j) {
            int col = n0 + wc * 64 + j * 16 + l16;
#pragma unroll
            for (int r = 0; r < 4; ++r)
                zx[(size_t)(row + r) * ZD + col] = acc[i][j][r] + bias[j];
        }
    }
}

// ---------------- fast activations (critical path) ----------------
__device__ __forceinline__ float sigmoid_fast(float x) {
    float e = __expf(-x);
    return __builtin_amdgcn_rcpf(1.f + e);
}
__device__ __forceinline__ float tanh_fast(float x) {
    float e = __expf(2.f * x);
    return 1.f - 2.f * __builtin_amdgcn_rcpf(e + 1.f);
}

// ---------------- phase-2 step loop: VERBATIM round-5 (11.96ms, passing), ------
// templated on handoff scope. LOCAL=true  -> sc0-only (XCD-L2 coherence point,
// valid only when all 64 active WGs share one XCD). LOCAL=false -> sc0 sc1 (LLC),
// byte-identical behavior to round 5. r7 proved the pre-spin zx prefetch placement
// is right (its latency overlaps the poll's vmcnt(0) wait — max, not sum).
template<bool LOCAL>
__device__ __forceinline__ void lstm_loop(int g, const unsigned* __restrict__ whp,
                                          const float* __restrict__ zx,
                                          float* __restrict__ out, unsigned* hslot,
                                          unsigned* lds_hh, float (*pbuf)[B2],
                                          float (*zx_lds)[64], int t) {
    const int seg  = t >> 6;           // 0..7 == wave index
    const int lane = t & 63;
    const int gate = lane >> 4;        // 0..3  [i,j,f,o]
    const int cidx = lane & 15;
    const int zcol = g * 16 + cidx + (gate << 10);

    // Wh slice -> 64 packed-fp16 dwords (compiler-managed; pinning proved harmful)
    unsigned wp[64];
    {
        const unsigned* wsrc = whp + ((size_t)zcol * 8 + seg) * 64;
#pragma unroll
        for (int j = 0; j < 64; ++j) wp[j] = wsrc[j];
    }

    // preload zx row 0 (wave 1); consumed in phase C of step 0
    if (t >= 64 && t < 128) {
        int l = t - 64;
        zx_lds[0][l] = zx[(size_t)0 * ZD + (size_t)(l >> 4) * 1024 + g * 16 + (l & 15)];
    }
    __syncthreads();   // cover zx_lds[0] for step-0 C-phase (outside the loop)

    float c_state = 0.f;
    int alive = 1;

    for (int s = 0; s < T_STEPS; ++s) {
        const int par = s & 1;
        // wave 1: issue zx prefetch for step s+1 BEFORE the spin (overlaps poll RT)
        float znext = 0.f;
        if (t >= 64 && t < 128 && s + 1 < T_STEPS) {
            int l = t - 64;
            znext = zx[(size_t)(s + 1) * ZD + (size_t)(l >> 4) * 1024 + g * 16 + (l & 15)];
        }
        // ---- A: acquire own slice — lanes 0..31 poll 16B = 4 tagged packets ----
        if (lane < 32 && alive) {
            const unsigned want = (unsigned)(s & 255);
            const unsigned* ap = hslot + (par << 10) + (seg << 7) + (lane << 2);
            uint4v pv;
            int it = 0;
            for (;;) {
                if constexpr (LOCAL)
                    asm volatile("global_load_dwordx4 %0, %1, off sc0\n\t"
                                 "s_waitcnt vmcnt(0)"
                                 : "=v"(pv) : "v"(ap) : "memory");
                else
                    asm volatile("global_load_dwordx4 %0, %1, off sc0 sc1\n\t"
                                 "s_waitcnt vmcnt(0)"
                                 : "=v"(pv) : "v"(ap) : "memory");
                unsigned bad = ((pv.x ^ want) | (pv.y ^ want) |
                                (pv.z ^ want) | (pv.w ^ want)) & 255u;
                if (bad == 0) break;
                if (++it > (1 << 22)) { alive = 0; break; }   // sticky bail, no hang
            }
            unsigned d0 = pk16(__uint_as_float(pv.x), __uint_as_float(pv.y));
            unsigned d1 = pk16(__uint_as_float(pv.z), __uint_as_float(pv.w));
            *(uint2*)&lds_hh[(seg << 6) + 2 * lane] = make_uint2(d0, d1);
        }
        // ---- B: 64 dot2 against fp16 weights (own slice) ----
        float a0 = 0.f, a1 = 0.f, a2 = 0.f, a3 = 0.f;
        const uint4* hp = (const uint4*)&lds_hh[seg << 6];
#pragma unroll
        for (int j = 0; j < 16; ++j) {
            uint4 hv = hp[j];    // same addr across wave: LDS broadcast, no conflict
            a0 = __builtin_amdgcn_fdot2(__builtin_bit_cast(h2v, wp[4 * j + 0]),
                                        __builtin_bit_cast(h2v, hv.x), a0, false);
            a1 = __builtin_amdgcn_fdot2(__builtin_bit_cast(h2v, wp[4 * j + 1]),
                                        __builtin_bit_cast(h2v, hv.y), a1, false);
            a2 = __builtin_amdgcn_fdot2(__builtin_bit_cast(h2v, wp[4 * j + 2]),
                                        __builtin_bit_cast(h2v, hv.z), a2, false);
            a3 = __builtin_amdgcn_fdot2(__builtin_bit_cast(h2v, wp[4 * j + 3]),
                                        __builtin_bit_cast(h2v, hv.w), a3, false);
        }
        pbuf[par][t] = (a0 + a1) + (a2 + a3);
        if (t >= 64 && t < 128)                  // park prefetched zx for next step
            zx_lds[(s + 1) & 1][t - 64] = znext;
        __syncthreads();                         // the ONLY barrier per step
        // ---- C: wave 0 reduces, gates, publishes ----
        if (t < 64) {
            float z = zx_lds[s & 1][t];
#pragma unroll
            for (int ss = 0; ss < 8; ++ss) z += pbuf[par][(ss << 6) + t];
            float zi = __shfl(z, cidx);
            float zj = __shfl(z, 16 + cidx);
            float zf = __shfl(z, 32 + cidx);
            float zo = __shfl(z, 48 + cidx);
            if (t < 16) {
                float fg = sigmoid_fast(zf + 1.0f);   // FORGET_BIAS = 1.0
                float ig = sigmoid_fast(zi);
                float og = sigmoid_fast(zo);
                c_state = c_state * fg + ig * tanh_fast(zj);
                float h = tanh_fast(c_state) * og;
                unsigned hb  = (__float_as_uint(h) + 0x80u) & 0xFFFFFF00u;
                unsigned pkt = hb | (unsigned)((s + 1) & 255);
                unsigned* pp = hslot + (((s + 1) & 1) << 10) + g * 16 + t;
                if constexpr (LOCAL)
                    asm volatile("global_store_dword %0, %1, off sc0"
                                 :: "v"(pp), "v"(pkt) : "memory");
                else
                    __hip_atomic_store(pp, pkt, __ATOMIC_RELAXED,
                                       __HIP_MEMORY_SCOPE_AGENT);
                out[(size_t)s * HD + g * 16 + t] = h;  // off critical path
            }
        }
    }
}

// ---------------- phase 2 kernel: census -> mode select -> loop ----------------
// Big grid (512): census XCDs via NAMED hwreg(HW_REG_XCC_ID) (m09-verified form;
// r6 used a numeric id guess -> zero active WGs -> zero output). Pigeonhole: 512
// co-resident WGs over 8 XCDs -> some XCD holds >=64 (cap/XCD = 2/CU*32CU = 64).
// Its first 64 (bid order) run LOCAL (sc0/XCD-L2 handoff). Census invalid or no
// full XCD -> GLOBAL fallback = exact round-5 protocol with g=bid<64. Small grid
// (64) -> GLOBAL directly (host fallback path).
__global__ __launch_bounds__(B2, 4) void lstm_seq(const unsigned* __restrict__ whp,
                                                  const float* __restrict__ zx,
                                                  float* __restrict__ out,
                                                  unsigned* hslot,
                                                  int* xtab, int* cnt) {
    __shared__ unsigned lds_hh[512];       // fp16-packed h: dword d = {h[2d], h[2d+1]}
    __shared__ float pbuf[2][B2];
    __shared__ float zx_lds[2][64];
    __shared__ int xcc_lds[NWG];
    __shared__ int sel[2];                 // {mode: 0 exit / 1 local / 2 global, g}
    const int t = threadIdx.x, bid = blockIdx.x;
    int mode, g;

    if ((int)gridDim.x >= NWG) {
        if (t == 0) {
            unsigned xcc;
            asm volatile("s_getreg_b32 %0, hwreg(HW_REG_XCC_ID)" : "=s"(xcc));
            __hip_atomic_store(&xtab[bid], (int)(xcc & 7) | 256, __ATOMIC_RELAXED,
                               __HIP_MEMORY_SCOPE_AGENT);
            __hip_atomic_fetch_add(cnt, 1, __ATOMIC_RELEASE, __HIP_MEMORY_SCOPE_AGENT);
            int it = 0;
            while (__hip_atomic_load(cnt, __ATOMIC_ACQUIRE,
                                     __HIP_MEMORY_SCOPE_AGENT) < (int)gridDim.x)
                if (++it > (1 << 22)) break;   // bail -> invalid census -> fallback
        }
        __syncthreads();
        if (t < NWG)
            xcc_lds[t] = __hip_atomic_load(&xtab[t], __ATOMIC_RELAXED,
                                           __HIP_MEMORY_SCOPE_AGENT);
        __syncthreads();
        if (t == 0) {
            int counts[8] = {};
            bool valid = true;
            for (int j = 0; j < NWG; ++j) {
                int v = xcc_lds[j];
                if (!(v & 256)) valid = false;   // entry never written -> invalid
                counts[v & 7]++;
            }
            int target = -1;
            if (valid)
                for (int xc = 0; xc < 8; ++xc)
                    if (counts[xc] >= G2) { target = xc; break; }
            if (target >= 0) {
                int mine = xcc_lds[bid] & 7;
                int rank = 0;
                for (int j = 0; j < bid; ++j) if ((xcc_lds[j] & 7) == mine) rank++;
                sel[0] = (mine == target && rank < G2) ? 1 : 0;
                sel[1] = rank;
            } else {                       // fallback: exact round-5 configuration
                sel[0] = (bid < G2) ? 2 : 0;
                sel[1] = bid;
            }
        }
        __syncthreads();
        if (sel[0] == 0) return;           // non-selected WGs free their CUs
        mode = sel[0];
        g    = sel[1];
    } else {                               // 64-WG host-fallback launch
        mode = 2;
        g    = bid;
    }

    if (mode == 1) lstm_loop<true >(g, whp, zx, out, hslot, lds_hh, pbuf, zx_lds, t);
    else           lstm_loop<false>(g, whp, zx, out, hslot, lds_hh, pbuf, zx_lds, t);
}

// ---------------- launch ----------------
extern "C" void kernel_launch(void* const* d_in, const int* in_sizes, int n_in,
                              void* d_out, int out_size, void* d_ws, size_t ws_size,
                              hipStream_t stream) {
    const float* x = (const float*)d_in[0];   // [8192,1024]
    const float* W = (const float*)d_in[1];   // [2048,4096]
    const float* b = (const float*)d_in[2];   // [4096]
    float* out = (float*)d_out;               // [8192,1024]

    char* ws = (char*)d_ws;
    // ws layout: zx 128MB | hslot 8KB | xtab 2KB | cnt | pad to 16KB | Wt/Whp 8MB
    float*          zxp   = (float*)ws;
    const size_t    ZXB   = (size_t)T_STEPS * ZD * sizeof(float);   // 134217728
    unsigned*       hslot = (unsigned*)(ws + ZXB);
    int*            xtab  = (int*)(ws + ZXB + 8192);
    int*            cnt   = (int*)(ws + ZXB + 8192 + 2048);
    unsigned short* Wt    = (unsigned short*)(ws + ZXB + 16384);
    unsigned*       Whp   = (unsigned*)(ws + ZXB + 16384);          // reuses Wt region

    // zero hslot (tag 0 = h_0) + xtab + cnt (ws is poisoned each call)
    hipMemsetAsync(hslot, 0, 16384, stream);

    // phase 0: pack Wx -> bf16 tiles
    wt_pack<<<dim3((IN_DIM * ZD) / 256), dim3(256), 0, stream>>>(W, Wt);

    // phase 1: ZX = x @ Wx + b
    zx_gemm<<<dim3(ZD / BN, T_STEPS / BM), dim3(256), 0, stream>>>(x, Wt, b, zxp);

    // phase 0b: pack Wh -> fp16 pairs into the now-dead Wt region (stream-ordered)
    whp_pack<<<dim3(128), dim3(256), 0, stream>>>(W, Whp);

    // phase 2: try the 512-WG census launch; fall back to the 64-WG round-5 grid
    void* args[] = { (void*)&Whp, (void*)&zxp, (void*)&out, (void*)&hslot,
                     (void*)&xtab, (void*)&cnt };
    int nb = 0;
    hipError_t qe = hipOccupancyMaxActiveBlocksPerMultiprocessor(
                        &nb, reinterpret_cast<const void*>(lstm_seq), B2, 0);
    hipError_t le = hipErrorUnknown;
    if (qe == hipSuccess && nb >= 2)
        le = hipLaunchCooperativeKernel((void*)lstm_seq, dim3(NWG), dim3(B2),
                                        args, 0, stream);
    if (le != hipSuccess)
        hipLaunchCooperativeKernel((void*)lstm_seq, dim3(G2), dim3(B2),
                                   args, 0, stream);
}